// Round 15
// baseline (20842.056 us; speedup 1.0000x reference)
//
#include <hip/hip_runtime.h>
#include <hip/hip_cooperative_groups.h>
#include <math.h>

typedef unsigned int u32x4 __attribute__((ext_vector_type(4)));

constexpr int T = 4096;   // SEQ_LEN
constexpr int R = 2048;   // RES_SIZE
constexpr int J = 128;    // INPUT_SIZE
constexpr float ONE_MINUS_LEAK = 0.1f;
constexpr float LEAK = 0.9f;
constexpr float INV_SQRT_R = 0.022097086912079608f;  // 1/sqrt(2048)

constexpr int NINST = 2;   // racing redundant instances (bit-identical)
constexpr int NWG   = 64 * NINST;
constexpr int NREP  = 2;   // slot replicas; 64 pollers per replica (R11 level)

// ---------------- Persistent kernel: racing-instance recurrence.
// Instance i = wg>>6 (64 WGs each) computes the FULL recurrence; both
// instances produce BIT-IDENTICAL values (same deterministic FMA/erf order,
// quantized exchanged state) and publish the same bits to the SAME slots
// (benign races). Row availability = min over instances -> convoy tail of
// the rendezvous is min-reduced. slots[2][NREP][R] u32: bits[31:8] = f32
// (low mantissa byte stolen, ~3e-7 quant -- R13-proven), bits[7:0] = t&0xFF.
// Lap rule: diff = (tag - want) & 0xFF; 0 = fresh, >=128 = stale(old),
// 1..127 = we were lapped -> whole-WG abort (flag + barrier + return)
// BEFORE any use/publish of corrupt data. Only a per-row-block laggard can
// be lapped (a lap requires the sibling instance to have published ahead),
// so >=1 instance per row-block survives: liveness + full out coverage.
// proj is computed in-kernel (u[t] staged to LDS, Win cols + bias in regs)
// so instances never read what another instance wrote (out is write-only).
__global__ __launch_bounds__(512) void esn_recur_kernel(
    const float* __restrict__ U, const float* __restrict__ Win,
    const float* __restrict__ Wres, const float* __restrict__ bias,
    float* __restrict__ out, unsigned* __restrict__ slots /* [2][NREP][R] */)
{
    const int wg   = blockIdx.x;
    const int tid  = threadIdx.x;
    const int wv   = tid >> 6;
    const int lane = tid & 63;
    const int rowbase = (wg & 63) * 32 + wv * 4;  // row-block = wg & 63
    const int rep  = wg & (NREP - 1);

    // 4 rows of Wres in registers (coalesced: 64 lanes x f32 per k).
    float w[4][32];
#pragma unroll
    for (int j = 0; j < 4; ++j) {
        const float* wr = Wres + (size_t)(rowbase + j) * R + lane;
#pragma unroll
        for (int k = 0; k < 32; ++k) w[j][k] = wr[k * 64];
    }
    // Win columns for the in-kernel input projection.
    float w2a[4], w2b[4];
#pragma unroll
    for (int j = 0; j < 4; ++j) {
        const float* wi = Win + (size_t)(rowbase + j) * J;
        w2a[j] = wi[lane];
        w2b[j] = wi[64 + lane];
    }
    const float biasr = (lane < 4) ? bias[rowbase + lane] : 0.f;

    __shared__ __align__(16) float xs[2][R];
    __shared__ __align__(16) float ul[2][J];
    __shared__ int s_abort;
    if (tid == 0) s_abort = 0;
    __syncthreads();                      // one-time init

    float xold = 0.f;    // lanes 0..3: previous state of row rowbase+lane
    long  spin = 0;      // cumulative guard: bugs -> fast wrong answer

    for (int t = 0; t < T; ++t) {
        // ---- Stage u[t] (512B) for the in-kernel projection.
        if (tid < 32)
            *(float4*)&ul[t & 1][4 * tid] =
                *(const float4*)(U + (size_t)t * J + 4 * tid);

        // ---- Poll x^{(t)}: thread owns slots 4tid..4tid+3 -> ONE dwordx4.
        const unsigned* p =
            slots + ((size_t)((t & 1) * NREP + rep)) * R + 4 * tid;
        const unsigned want = (unsigned)t & 0xFFu;
        u32x4 v;
        while (true) {
            asm volatile(
                "global_load_dwordx4 %0, %1, off sc0 sc1\n\t"
                "s_waitcnt vmcnt(0)"
                : "=&v"(v) : "v"(p) : "memory");
            unsigned d0 = (v[0] - want) & 0xFFu, d1 = (v[1] - want) & 0xFFu;
            unsigned d2 = (v[2] - want) & 0xFFu, d3 = (v[3] - want) & 0xFFu;
            if ((d0 | d1 | d2 | d3) == 0u) break;          // all fresh
            if (((d0 && d0 < 128u) | (d1 && d1 < 128u) |
                 (d2 && d2 < 128u) | (d3 && d3 < 128u)) ||
                ++spin > (1L << 26)) {                     // lapped or bug
                s_abort = 1;
                break;
            }
        }
        // Strip tags, stage 16B to LDS.
        float4 xv = make_float4(__uint_as_float(v[0] & 0xFFFFFF00u),
                                __uint_as_float(v[1] & 0xFFFFFF00u),
                                __uint_as_float(v[2] & 0xFFFFFF00u),
                                __uint_as_float(v[3] & 0xFFFFFF00u));
        *(float4*)&xs[t & 1][4 * tid] = xv;
        __syncthreads();   // stage -> dot join; also publishes s_abort
        if (s_abort) return;   // lapped laggard: drain without publishing

        // ---- x into registers once (2-way LDS alias: free), reuse 4 rows.
        const float* x = xs[t & 1];
        float xr[32];
#pragma unroll
        for (int k = 0; k < 32; ++k) xr[k] = x[k * 64 + lane];
        const float uu0 = ul[t & 1][lane];
        const float uu1 = ul[t & 1][64 + lane];

#pragma unroll
        for (int j = 0; j < 4; ++j) {
            float a0 = 0.f, a1 = 0.f, a2 = 0.f, a3 = 0.f;
#pragma unroll
            for (int k = 0; k < 8; ++k) {
                a0 = fmaf(w[j][4 * k + 0], xr[4 * k + 0], a0);
                a1 = fmaf(w[j][4 * k + 1], xr[4 * k + 1], a1);
                a2 = fmaf(w[j][4 * k + 2], xr[4 * k + 2], a2);
                a3 = fmaf(w[j][4 * k + 3], xr[4 * k + 3], a3);
            }
            a0 = fmaf(w2a[j], uu0, a0);          // input projection
            a1 = fmaf(w2b[j], uu1, a1);
            float acc = (a0 + a1) + (a2 + a3);
#pragma unroll
            for (int off = 32; off > 0; off >>= 1)
                acc += __shfl_xor(acc, off);

            // Publish row rowbase+j IMMEDIATELY (earliest visibility).
            if (lane == j) {
                const float pre  = acc + biasr;
                const float xnew = ONE_MINUS_LEAK * xold +
                                   LEAK * erff(pre) * INV_SQRT_R;
                xold = xnew;
                const unsigned bits =
                    ((__float_as_uint(xnew) + 0x80u) & 0xFFFFFF00u) |
                    ((unsigned)(t + 1) & 0xFFu);
                const size_t pb = (size_t)(((t + 1) & 1) * NREP) * R
                                + rowbase + j;
#pragma unroll
                for (int g = 0; g < NREP; ++g)
                    __hip_atomic_store(&slots[pb + (size_t)g * R], bits,
                                       __ATOMIC_RELAXED,
                                       __HIP_MEMORY_SCOPE_AGENT);
                out[(size_t)t * R + rowbase + j] = xnew;  // states output
            }
        }
    }
}

extern "C" void kernel_launch(void* const* d_in, const int* in_sizes, int n_in,
                              void* d_out, int out_size, void* d_ws, size_t ws_size,
                              hipStream_t stream) {
    const float* U    = (const float*)d_in[0];  // (4096,128)
    const float* Win  = (const float*)d_in[1];  // (2048,128)
    const float* Wres = (const float*)d_in[2];  // (2048,2048)
    const float* bias = (const float*)d_in[3];  // (2048,)
    float* out = (float*)d_out;                 // (4096,2048)
    unsigned* slots = (unsigned*)d_ws;          // [2][NREP][R] u32

    // All-zero slots: tag 0 == (t=0)&0xFF, value bits 0 == x^0 = 0. Valid.
    hipMemsetAsync(slots, 0, (size_t)2 * NREP * R * sizeof(unsigned), stream);

    void* args[] = { (void*)&U, (void*)&Win, (void*)&Wres, (void*)&bias,
                     (void*)&out, (void*)&slots };
    hipLaunchCooperativeKernel((const void*)esn_recur_kernel,
                               dim3(NWG), dim3(512), args, 0, stream);
}

// Round 16
// 17985.957 us; speedup vs baseline: 1.1588x; 1.1588x over previous
//
#include <hip/hip_runtime.h>
#include <hip/hip_cooperative_groups.h>
#include <math.h>

typedef unsigned int u32x4 __attribute__((ext_vector_type(4)));
typedef unsigned long long ull;

constexpr int T = 4096;   // SEQ_LEN
constexpr int R = 2048;   // RES_SIZE
constexpr int J = 128;    // INPUT_SIZE
constexpr float ONE_MINUS_LEAK = 0.1f;
constexpr float LEAK = 0.9f;
constexpr float INV_SQRT_R = 0.022097086912079608f;  // 1/sqrt(2048)

constexpr int NWG  = 64;   // rendezvous participants (R11-proven optimum)
constexpr int NREP = 4;    // 16 WGs/replica -> 64 readers per slot line

// ---------------- Kernel A: proj[t][r] = input[t] . W_in[r] + bias[r] -> d_out
__global__ __launch_bounds__(256) void esn_proj_kernel(
    const float* __restrict__ U, const float* __restrict__ Win,
    const float* __restrict__ bias, float* __restrict__ out)
{
    __shared__ float As[16][129];
    __shared__ float Bs[16][129];
    const int tb = blockIdx.x * 16;
    const int rb = blockIdx.y * 16;
    const int tid = threadIdx.x;

    for (int i = tid; i < 16 * J; i += 256) {
        int r = i >> 7, c = i & 127;
        As[r][c] = U[(size_t)(tb + r) * J + c];
        Bs[r][c] = Win[(size_t)(rb + r) * J + c];
    }
    __syncthreads();

    const int ti = tid >> 4;
    const int rj = tid & 15;
    float acc = 0.f;
#pragma unroll
    for (int k = 0; k < J; ++k) acc = fmaf(As[ti][k], Bs[rj][k], acc);
    out[(size_t)(tb + ti) * R + (rb + rj)] = acc + bias[rb + rj];
}

// ---------------- Kernel B: R11's protocol + NREP=4 + immediate publish
// + 1 WG/CU (96KB LDS pad). 64 WGs x 512 threads; WG w owns rows
// [32w,32w+32); wave v owns rows rowbase=32w+4v..+3. slots[2][NREP][R] ull:
// lo32 = f32 bits, hi32 = tag (step index of the state). Each WG polls
// replica (w&3); thread owns slots {2tid,2tid+1} and {1024+2tid,+1}
// (R5/R11-verbatim poll). Publish = one 8B sc0sc1 store per replica from
// lane j, issued IMMEDIATELY after row j's reduce. Skew<=1 tag induction
// identical to R4/R5/R11 (publish of t+1 follows this wave's detect of all
// tags t + the stage barrier).
__global__ __launch_bounds__(512) void esn_recur_kernel(
    const float* __restrict__ Wres, float* __restrict__ out,
    ull* __restrict__ slots /* [2][NREP][R] */)
{
    extern __shared__ char dyn_pad[];   // 96KB pad: forces 1 WG/CU
    (void)dyn_pad;

    const int wg   = blockIdx.x;
    const int tid  = threadIdx.x;
    const int wv   = tid >> 6;
    const int lane = tid & 63;
    const int rowbase = wg * 32 + wv * 4;   // this wave's 4 rows
    const int rep  = wg & (NREP - 1);

    // 4 rows of weights in registers (coalesced: 64 lanes x f32 per k).
    float w[4][32];
#pragma unroll
    for (int j = 0; j < 4; ++j) {
        const float* wr = Wres + (size_t)(rowbase + j) * R + lane;
#pragma unroll
        for (int k = 0; k < 32; ++k) w[j][k] = wr[k * 64];
    }

    __shared__ __align__(16) float xs[2][R];
    float xold = 0.f;    // lanes 0..3: previous state of row rowbase+lane
    long  spin = 0;      // cumulative guard: bugs -> fast wrong answer

    for (int t = 0; t < T; ++t) {
        // Input projection prefetch (latency hides under the poll).
        float proj = (lane < 4) ? out[(size_t)t * R + rowbase + lane] : 0.f;

        // ---- Poll x^{(t)} in our replica (R5/R11-verbatim shape).
        const ull* src = slots + ((size_t)((t & 1) * NREP + rep)) * R;
        const ull* p0 = src + 2 * tid;
        const ull* p1 = src + 1024 + 2 * tid;
        const unsigned want = (unsigned)t;
        u32x4 v0, v1;
        while (true) {
            asm volatile(
                "global_load_dwordx4 %0, %2, off sc0 sc1\n\t"
                "global_load_dwordx4 %1, %3, off sc0 sc1\n\t"
                "s_waitcnt vmcnt(0)"
                : "=&v"(v0), "=&v"(v1)
                : "v"(p0), "v"(p1)
                : "memory");
            if (v0[1] == want && v0[3] == want &&
                v1[1] == want && v1[3] == want) break;
            if (++spin > (1L << 26)) break;
        }
        float* xb = xs[t & 1];
        xb[2 * tid]        = __uint_as_float(v0[0]);
        xb[2 * tid + 1]    = __uint_as_float(v0[2]);
        xb[2 * tid + 1024] = __uint_as_float(v1[0]);
        xb[2 * tid + 1025] = __uint_as_float(v1[2]);
        __syncthreads();   // the only barrier per step: stage -> dot join

        // ---- x into registers once (2-way LDS alias: free), reuse 4 rows.
        const float* x = xs[t & 1];
        float xr[32];
#pragma unroll
        for (int k = 0; k < 32; ++k) xr[k] = x[k * 64 + lane];

#pragma unroll
        for (int j = 0; j < 4; ++j) {
            float a0 = 0.f, a1 = 0.f, a2 = 0.f, a3 = 0.f;
#pragma unroll
            for (int k = 0; k < 8; ++k) {
                a0 = fmaf(w[j][4 * k + 0], xr[4 * k + 0], a0);
                a1 = fmaf(w[j][4 * k + 1], xr[4 * k + 1], a1);
                a2 = fmaf(w[j][4 * k + 2], xr[4 * k + 2], a2);
                a3 = fmaf(w[j][4 * k + 3], xr[4 * k + 3], a3);
            }
            float acc = (a0 + a1) + (a2 + a3);
#pragma unroll
            for (int off = 32; off > 0; off >>= 1)
                acc += __shfl_xor(acc, off);

            // Publish row rowbase+j IMMEDIATELY after its reduce.
            if (lane == j) {
                const float pre  = acc + proj;   // proj includes bias
                const float xnew = ONE_MINUS_LEAK * xold +
                                   LEAK * erff(pre) * INV_SQRT_R;
                xold = xnew;
                const ull packed = ((ull)(unsigned)(t + 1) << 32) |
                                   (ull)__float_as_uint(xnew);
                const size_t pb = (size_t)(((t + 1) & 1) * NREP) * R
                                + rowbase + j;
#pragma unroll
                for (int g = 0; g < NREP; ++g)
                    __hip_atomic_store(&slots[pb + (size_t)g * R], packed,
                                       __ATOMIC_RELAXED,
                                       __HIP_MEMORY_SCOPE_AGENT);
                out[(size_t)t * R + rowbase + j] = xnew;  // states output
            }
        }
    }
}

extern "C" void kernel_launch(void* const* d_in, const int* in_sizes, int n_in,
                              void* d_out, int out_size, void* d_ws, size_t ws_size,
                              hipStream_t stream) {
    const float* U    = (const float*)d_in[0];  // (4096,128)
    const float* Win  = (const float*)d_in[1];  // (2048,128)
    const float* Wres = (const float*)d_in[2];  // (2048,2048)
    const float* bias = (const float*)d_in[3];  // (2048,)
    float* out = (float*)d_out;                 // (4096,2048)
    ull* slots = (ull*)d_ws;                    // [2][NREP][R]

    // tag0/value0 everywhere == valid x^0 = 0 in buf[0]; graph-replay safe.
    hipMemsetAsync(slots, 0, (size_t)2 * NREP * R * sizeof(ull), stream);

    dim3 pgrid(T / 16, R / 16);
    esn_proj_kernel<<<pgrid, dim3(256), 0, stream>>>(U, Win, bias, out);

    // 16KB static + 96KB dynamic LDS -> exactly 1 WG per CU (64 CUs used).
    void* args[] = { (void*)&Wres, (void*)&out, (void*)&slots };
    hipLaunchCooperativeKernel((const void*)esn_recur_kernel,
                               dim3(NWG), dim3(512), args, 96 * 1024, stream);
}

// Round 17
// 11387.237 us; speedup vs baseline: 1.8303x; 1.5795x over previous
//
#include <hip/hip_runtime.h>
#include <hip/hip_cooperative_groups.h>
#include <math.h>

typedef unsigned int u32x4 __attribute__((ext_vector_type(4)));
typedef unsigned long long ull;

constexpr int T = 4096;   // SEQ_LEN
constexpr int R = 2048;   // RES_SIZE
constexpr int J = 128;    // INPUT_SIZE
constexpr float ONE_MINUS_LEAK = 0.1f;
constexpr float LEAK = 0.9f;
constexpr float INV_SQRT_R = 0.022097086912079608f;  // 1/sqrt(2048)

constexpr int NWG  = 64;   // rendezvous participants (proven optimum, R11)
constexpr int NREP = 2;    // slot replicas; 32 sharers per slot line

// ---------------- Kernel A: proj[t][r] = input[t] . W_in[r] + bias[r] -> d_out
__global__ __launch_bounds__(256) void esn_proj_kernel(
    const float* __restrict__ U, const float* __restrict__ Win,
    const float* __restrict__ bias, float* __restrict__ out)
{
    __shared__ float As[16][129];
    __shared__ float Bs[16][129];
    const int tb = blockIdx.x * 16;
    const int rb = blockIdx.y * 16;
    const int tid = threadIdx.x;

    for (int i = tid; i < 16 * J; i += 256) {
        int r = i >> 7, c = i & 127;
        As[r][c] = U[(size_t)(tb + r) * J + c];
        Bs[r][c] = Win[(size_t)(rb + r) * J + c];
    }
    __syncthreads();

    const int ti = tid >> 4;
    const int rj = tid & 15;
    float acc = 0.f;
#pragma unroll
    for (int k = 0; k < J; ++k) acc = fmaf(As[ti][k], Bs[rj][k], acc);
    out[(size_t)(tb + ti) * R + (rb + rj)] = acc + bias[rb + rj];
}

// ---------------- Kernel B: R11 final. 64 WGs x 512 threads; WG w owns rows
// [32w, 32w+32); wave v owns 4 rows rowbase = 32w+4v..+3.
// slots[2][NREP][R] ull: lo32 = f32 bits, hi32 = tag (step index of the
// state). Publish = one 8B sc0sc1 store per replica from lanes 0..3
// (coalesced). Each WG polls replica (w&1): thread owns slots {2tid,2tid+1}
// and {1024+2tid,+1}, swept with 2 in-flight dwordx4 under one vmcnt(0).
// Skew<=1 tag induction: tag t+1 is published into buffer (t+1)&1 only
// after this WG's poll(t) completed; a consumer still reading that buffer
// at t-1 would contradict all-tags-t having been observed. Exact-match
// tags make stale values unmistakable; 4096 < 2^32 so tags never wrap.
__global__ __launch_bounds__(512) void esn_recur_kernel(
    const float* __restrict__ Wres, float* __restrict__ out,
    ull* __restrict__ slots /* [2][NREP][R] */)
{
    const int wg   = blockIdx.x;
    const int tid  = threadIdx.x;
    const int wv   = tid >> 6;
    const int lane = tid & 63;
    const int rowbase = wg * 32 + wv * 4;   // this wave's 4 rows
    const int rep  = wg & (NREP - 1);

    // 4 rows of weights in registers (coalesced: 64 lanes x f32 per k).
    float w[4][32];
#pragma unroll
    for (int j = 0; j < 4; ++j) {
        const float* wr = Wres + (size_t)(rowbase + j) * R + lane;
#pragma unroll
        for (int k = 0; k < 32; ++k) w[j][k] = wr[k * 64];
    }

    __shared__ __align__(16) float xs[2][R];
    float xold = 0.f;    // lanes 0..3: previous state of row rowbase+lane
    long  spin = 0;      // cumulative guard: bugs -> fast wrong answer

    for (int t = 0; t < T; ++t) {
        // Input projection prefetch (latency hides under the poll).
        float proj = (lane < 4) ? out[(size_t)t * R + rowbase + lane] : 0.f;

        // ---- Poll x^{(t)} in our replica.
        const ull* src = slots + ((size_t)((t & 1) * NREP + rep)) * R;
        const ull* p0 = src + 2 * tid;
        const ull* p1 = src + 1024 + 2 * tid;
        const unsigned want = (unsigned)t;
        u32x4 v0, v1;
        while (true) {
            asm volatile(
                "global_load_dwordx4 %0, %2, off sc0 sc1\n\t"
                "global_load_dwordx4 %1, %3, off sc0 sc1\n\t"
                "s_waitcnt vmcnt(0)"
                : "=&v"(v0), "=&v"(v1)
                : "v"(p0), "v"(p1)
                : "memory");
            if (v0[1] == want && v0[3] == want &&
                v1[1] == want && v1[3] == want) break;
            if (++spin > (1L << 26)) break;
        }
        float* xb = xs[t & 1];
        xb[2 * tid]        = __uint_as_float(v0[0]);
        xb[2 * tid + 1]    = __uint_as_float(v0[2]);
        xb[2 * tid + 1024] = __uint_as_float(v1[0]);
        xb[2 * tid + 1025] = __uint_as_float(v1[2]);
        __syncthreads();   // the only barrier per step: stage -> dot join

        // ---- x into registers once (2-way LDS alias: free), reuse 4 rows.
        const float* x = xs[t & 1];
        float xr[32];
#pragma unroll
        for (int k = 0; k < 32; ++k) xr[k] = x[k * 64 + lane];

        float mysum = 0.f;
#pragma unroll
        for (int j = 0; j < 4; ++j) {
            float a0 = 0.f, a1 = 0.f, a2 = 0.f, a3 = 0.f;
#pragma unroll
            for (int k = 0; k < 8; ++k) {
                a0 = fmaf(w[j][4 * k + 0], xr[4 * k + 0], a0);
                a1 = fmaf(w[j][4 * k + 1], xr[4 * k + 1], a1);
                a2 = fmaf(w[j][4 * k + 2], xr[4 * k + 2], a2);
                a3 = fmaf(w[j][4 * k + 3], xr[4 * k + 3], a3);
            }
            float acc = (a0 + a1) + (a2 + a3);
#pragma unroll
            for (int off = 32; off > 0; off >>= 1)
                acc += __shfl_xor(acc, off);
            if (lane == j) mysum = acc;          // static j -> cndmask
        }

        // ---- Lanes 0..3 finalize their row, publish, write output.
        if (lane < 4) {
            const float pre  = mysum + proj;     // proj includes bias
            const float xnew = ONE_MINUS_LEAK * xold +
                               LEAK * erff(pre) * INV_SQRT_R;
            xold = xnew;
            const ull packed = ((ull)(unsigned)(t + 1) << 32) |
                               (ull)__float_as_uint(xnew);
            const size_t pb = (size_t)(((t + 1) & 1) * NREP) * R
                            + rowbase + lane;
#pragma unroll
            for (int g = 0; g < NREP; ++g)
                __hip_atomic_store(&slots[pb + (size_t)g * R], packed,
                                   __ATOMIC_RELAXED, __HIP_MEMORY_SCOPE_AGENT);
            out[(size_t)t * R + rowbase + lane] = xnew;  // states output
        }
    }
}

extern "C" void kernel_launch(void* const* d_in, const int* in_sizes, int n_in,
                              void* d_out, int out_size, void* d_ws, size_t ws_size,
                              hipStream_t stream) {
    const float* U    = (const float*)d_in[0];  // (4096,128)
    const float* Win  = (const float*)d_in[1];  // (2048,128)
    const float* Wres = (const float*)d_in[2];  // (2048,2048)
    const float* bias = (const float*)d_in[3];  // (2048,)
    float* out = (float*)d_out;                 // (4096,2048)
    ull* slots = (ull*)d_ws;                    // [2][NREP][R]

    // tag0/value0 everywhere == valid x^0 = 0 in buf[0]; graph-replay safe.
    hipMemsetAsync(slots, 0, (size_t)2 * NREP * R * sizeof(ull), stream);

    dim3 pgrid(T / 16, R / 16);
    esn_proj_kernel<<<pgrid, dim3(256), 0, stream>>>(U, Win, bias, out);

    void* args[] = { (void*)&Wres, (void*)&out, (void*)&slots };
    hipLaunchCooperativeKernel((const void*)esn_recur_kernel,
                               dim3(NWG), dim3(512), args, 0, stream);
}